// Round 1
// baseline (9454.004 us; speedup 1.0000x reference)
//
#include <hip/hip_runtime.h>

// Chamfer distance between two 131072-point fp32 clouds (first 3 of 4 columns).
// Strategy: brute-force all-pairs min squared distance, both directions.
//   d_ij = |x_i|^2 + |y_j|^2 - 2 x_i.y_j ;  min_j folds |x_i|^2 out.
// y-stream is wave-uniform -> scalar loads (s_load) -> ~5 VALU instr per pair.

__global__ __launch_bounds__(256) void pack_kernel(
    const float4* __restrict__ in, float4* __restrict__ out, int n) {
    int i = blockIdx.x * 256 + threadIdx.x;
    if (i < n) {
        float4 a = in[i];
        float s = fmaf(a.x, a.x, fmaf(a.y, a.y, a.z * a.z));
        out[i] = make_float4(a.x, a.y, a.z, s);
    }
}

// X: packed query points (x,y,z,|x|^2). Y: packed reference points.
// Adds sum_i min_j |x_i - y_j|^2 into *acc (double, device-scope atomic).
__global__ __launch_bounds__(256) void chamfer_dir_kernel(
    const float4* __restrict__ X, const float4* __restrict__ Y,
    int m, double* __restrict__ acc) {
    int i = blockIdx.x * 256 + threadIdx.x;
    float4 x = X[i];
    float mn = 3.4e38f;
    // m is a multiple of 8 (131072). Loop body: wave-uniform y loads
    // (scalar pipe), 4 VALU per pair + amortized min.
    for (int j = 0; j < m; j += 8) {
#pragma unroll
        for (int u = 0; u < 8; u += 2) {
            float4 ya = Y[j + u];
            float4 yb = Y[j + u + 1];
            float da = fmaf(x.x, ya.x, fmaf(x.y, ya.y, x.z * ya.z));
            float db = fmaf(x.x, yb.x, fmaf(x.y, yb.y, x.z * yb.z));
            float ea = fmaf(-2.0f, da, ya.w);  // |y|^2 - 2 x.y
            float eb = fmaf(-2.0f, db, yb.w);
            mn = fminf(fminf(mn, ea), eb);     // hope: v_min3_f32
        }
    }
    float v = x.w + mn;  // actual min squared distance for point i

    // block reduction: wave shuffle then LDS across the 4 waves
    for (int off = 32; off > 0; off >>= 1) v += __shfl_down(v, off);
    __shared__ float partial[4];
    int lane = threadIdx.x & 63;
    int wid = threadIdx.x >> 6;
    if (lane == 0) partial[wid] = v;
    __syncthreads();
    if (threadIdx.x == 0) {
        float bs = (partial[0] + partial[1]) + (partial[2] + partial[3]);
        atomicAdd(acc, (double)bs);
    }
}

// Fallback (no workspace): direct |x-y|^2, 7 VALU per pair, reads raw inputs.
__global__ __launch_bounds__(256) void chamfer_raw_kernel(
    const float4* __restrict__ Xr, const float4* __restrict__ Yr,
    int m, double* __restrict__ acc) {
    int i = blockIdx.x * 256 + threadIdx.x;
    float4 x = Xr[i];
    float mn = 3.4e38f;
    for (int j = 0; j < m; j += 4) {
#pragma unroll
        for (int u = 0; u < 4; ++u) {
            float4 y = Yr[j + u];
            float dx = x.x - y.x, dy = x.y - y.y, dz = x.z - y.z;
            float d = fmaf(dx, dx, fmaf(dy, dy, dz * dz));
            mn = fminf(mn, d);
        }
    }
    float v = mn;
    for (int off = 32; off > 0; off >>= 1) v += __shfl_down(v, off);
    __shared__ float partial[4];
    int lane = threadIdx.x & 63;
    int wid = threadIdx.x >> 6;
    if (lane == 0) partial[wid] = v;
    __syncthreads();
    if (threadIdx.x == 0) {
        float bs = (partial[0] + partial[1]) + (partial[2] + partial[3]);
        atomicAdd(acc, (double)bs);
    }
}

__global__ void finalize_kernel(const double* __restrict__ acc,
                                float* __restrict__ out, int n) {
    out[0] = (float)(acc[0] / (double)n);
}

extern "C" void kernel_launch(void* const* d_in, const int* in_sizes, int n_in,
                              void* d_out, int out_size, void* d_ws, size_t ws_size,
                              hipStream_t stream) {
    const float4* pred = (const float4*)d_in[0];
    const float4* targ = (const float4*)d_in[1];
    float* out = (float*)d_out;
    int n = in_sizes[0] / 4;  // 131072 points
    int nblk = (n + 255) / 256;

    char* ws = (char*)d_ws;
    double* acc = (double*)ws;  // 8B accumulator at ws[0]
    // zero the accumulator every launch (ws is poisoned, never re-poisoned)
    hipMemsetAsync(acc, 0, sizeof(double), stream);

    size_t need = 64 + 2ull * (size_t)n * sizeof(float4);
    if (ws_size >= need) {
        float4* P = (float4*)(ws + 64);
        float4* T = P + n;
        pack_kernel<<<nblk, 256, 0, stream>>>(pred, P, n);
        pack_kernel<<<nblk, 256, 0, stream>>>(targ, T, n);
        chamfer_dir_kernel<<<nblk, 256, 0, stream>>>(P, T, n, acc);
        chamfer_dir_kernel<<<nblk, 256, 0, stream>>>(T, P, n, acc);
    } else {
        chamfer_raw_kernel<<<nblk, 256, 0, stream>>>(pred, targ, n, acc);
        chamfer_raw_kernel<<<nblk, 256, 0, stream>>>(targ, pred, n, acc);
    }
    finalize_kernel<<<1, 1, 0, stream>>>(acc, out, n);
}

// Round 2
// 3246.004 us; speedup vs baseline: 2.9125x; 2.9125x over previous
//
#include <hip/hip_runtime.h>

// Chamfer distance, two 131072-point fp32 clouds (first 3 of 4 columns).
// d_ij = |x|^2 + |y|^2 - 2 x.y ; fold |x|^2 out of the min, fold -2 into x.
// y-stream is wave-uniform -> scalar s_load (free); 3.5 VALU/pair.
// y-range split into SPLIT segments for occupancy; partials combined via
// atomicMin on an order-preserving uint encoding of the float distance.

#define SPLIT 16
#define PTS 4

__global__ __launch_bounds__(256) void pack_kernel(
    const float4* __restrict__ in, float4* __restrict__ out, int n) {
    int i = blockIdx.x * 256 + threadIdx.x;
    if (i < n) {
        float4 a = in[i];
        float s = fmaf(a.x, a.x, fmaf(a.y, a.y, a.z * a.z));
        out[i] = make_float4(a.x, a.y, a.z, s);
    }
}

__device__ __forceinline__ unsigned int enc_f32(float f) {
    unsigned int u = __float_as_uint(f);
    return (u & 0x80000000u) ? ~u : (u | 0x80000000u);
}
__device__ __forceinline__ float dec_f32(unsigned int u) {
    u = (u & 0x80000000u) ? (u ^ 0x80000000u) : ~u;
    return __uint_as_float(u);
}

// X packed (x,y,z,|x|^2), Y packed likewise. Each block handles 1024 x-points
// (4 per thread) against y-segment blockIdx.y. Result: atomicMin into mins[i].
__global__ __launch_bounds__(256) void chamfer_dir_kernel(
    const float4* __restrict__ X, const float4* __restrict__ Y,
    int m, unsigned int* __restrict__ mins) {
    int base = blockIdx.x * (256 * PTS) + threadIdx.x;
    float x2x[PTS], x2y[PTS], x2z[PTS], xw[PTS], mn[PTS];
#pragma unroll
    for (int p = 0; p < PTS; ++p) {
        float4 x = X[base + p * 256];
        x2x[p] = -2.0f * x.x;  // exact scale
        x2y[p] = -2.0f * x.y;
        x2z[p] = -2.0f * x.z;
        xw[p] = x.w;
        mn[p] = 3.4e38f;
    }
    int seglen = m / SPLIT;
    int j0 = blockIdx.y * seglen;
    int j1 = j0 + seglen;
    for (int j = j0; j < j1; j += 8) {
#pragma unroll
        for (int u = 0; u < 8; u += 2) {
            float4 ya = Y[j + u];      // wave-uniform -> scalar pipe
            float4 yb = Y[j + u + 1];
#pragma unroll
            for (int p = 0; p < PTS; ++p) {
                float ea = fmaf(x2x[p], ya.x,
                             fmaf(x2y[p], ya.y, fmaf(x2z[p], ya.z, ya.w)));
                float eb = fmaf(x2x[p], yb.x,
                             fmaf(x2y[p], yb.y, fmaf(x2z[p], yb.z, yb.w)));
                mn[p] = fminf(fminf(mn[p], ea), eb);  // -> v_min3_f32
            }
        }
    }
#pragma unroll
    for (int p = 0; p < PTS; ++p) {
        float v = xw[p] + mn[p];  // actual min squared distance (partial)
        atomicMin(&mins[base + p * 256], enc_f32(v));
    }
}

__global__ __launch_bounds__(256) void reduce_kernel(
    const unsigned int* __restrict__ mins, int total, double* __restrict__ acc) {
    float s = 0.0f;
    for (int i = blockIdx.x * 256 + threadIdx.x; i < total; i += gridDim.x * 256)
        s += dec_f32(mins[i]);
    for (int off = 32; off > 0; off >>= 1) s += __shfl_down(s, off);
    __shared__ float partial[4];
    int lane = threadIdx.x & 63, wid = threadIdx.x >> 6;
    if (lane == 0) partial[wid] = s;
    __syncthreads();
    if (threadIdx.x == 0)
        atomicAdd(acc, (double)((partial[0] + partial[1]) + (partial[2] + partial[3])));
}

__global__ void finalize_kernel(const double* __restrict__ acc,
                                float* __restrict__ out, int n) {
    out[0] = (float)(acc[0] / (double)n);
}

// Fallback (tiny workspace): direct all-pairs, slow but correct.
__global__ __launch_bounds__(256) void chamfer_raw_kernel(
    const float4* __restrict__ Xr, const float4* __restrict__ Yr,
    int m, double* __restrict__ acc) {
    int i = blockIdx.x * 256 + threadIdx.x;
    float4 x = Xr[i];
    float mn = 3.4e38f;
    for (int j = 0; j < m; j += 4) {
#pragma unroll
        for (int u = 0; u < 4; ++u) {
            float4 y = Yr[j + u];
            float dx = x.x - y.x, dy = x.y - y.y, dz = x.z - y.z;
            mn = fminf(mn, fmaf(dx, dx, fmaf(dy, dy, dz * dz)));
        }
    }
    float v = mn;
    for (int off = 32; off > 0; off >>= 1) v += __shfl_down(v, off);
    __shared__ float partial[4];
    int lane = threadIdx.x & 63, wid = threadIdx.x >> 6;
    if (lane == 0) partial[wid] = v;
    __syncthreads();
    if (threadIdx.x == 0)
        atomicAdd(acc, (double)((partial[0] + partial[1]) + (partial[2] + partial[3])));
}

extern "C" void kernel_launch(void* const* d_in, const int* in_sizes, int n_in,
                              void* d_out, int out_size, void* d_ws, size_t ws_size,
                              hipStream_t stream) {
    const float4* pred = (const float4*)d_in[0];
    const float4* targ = (const float4*)d_in[1];
    float* out = (float*)d_out;
    int n = in_sizes[0] / 4;  // 131072 points
    int nblk = (n + 255) / 256;

    char* ws = (char*)d_ws;
    double* acc = (double*)ws;
    hipMemsetAsync(acc, 0, sizeof(double), stream);

    size_t need = 64 + 2ull * n * sizeof(float4) + 2ull * n * sizeof(unsigned int);
    if (ws_size >= need && (n % (256 * PTS * 1)) == 0 && (n % SPLIT) == 0) {
        float4* P = (float4*)(ws + 64);
        float4* T = P + n;
        unsigned int* minPT = (unsigned int*)(T + n);  // [2n]: p2t then t2p
        pack_kernel<<<nblk, 256, 0, stream>>>(pred, P, n);
        pack_kernel<<<nblk, 256, 0, stream>>>(targ, T, n);
        hipMemsetAsync(minPT, 0xFF, 2ull * n * sizeof(unsigned int), stream);
        dim3 grid(n / (256 * PTS), SPLIT);
        chamfer_dir_kernel<<<grid, 256, 0, stream>>>(P, T, n, minPT);
        chamfer_dir_kernel<<<grid, 256, 0, stream>>>(T, P, n, minPT + n);
        reduce_kernel<<<256, 256, 0, stream>>>(minPT, 2 * n, acc);
    } else {
        chamfer_raw_kernel<<<nblk, 256, 0, stream>>>(pred, targ, n, acc);
        chamfer_raw_kernel<<<nblk, 256, 0, stream>>>(targ, pred, n, acc);
    }
    finalize_kernel<<<1, 1, 0, stream>>>(acc, out, n);
}